// Round 2
// baseline (234.452 us; speedup 1.0000x reference)
//
#include <hip/hip_runtime.h>
#include <hip/hip_bf16.h>
#include <math.h>

#define INPUT_DIM 256
#define OUT_DIM   256
#define NDEG      8                    // degree+1
#define KTOT      (INPUT_DIM * NDEG)   // 2048
#define NROWS     (16 * 2048)          // 32768

#define BM  64
#define BN  128
#define BK  64                         // 8 inputs * 8 degrees per K-chunk
#define NK  (KTOT / BK)                // 32
#define LDT 72                         // padded LDS row stride (144 B -> 2-way-only conflicts, free per m136)

typedef __bf16 bf16x8 __attribute__((ext_vector_type(8)));
typedef float  f32x4  __attribute__((ext_vector_type(4)));

// ---------------------------------------------------------------------------
// Kernel 1: reorder coeffs  C[i][o][d] (fp32)  ->  Bt[o][i*8+d] (bf16)
// ---------------------------------------------------------------------------
__global__ __launch_bounds__(256) void reorder_coeffs(const float* __restrict__ C,
                                                      __bf16* __restrict__ Bt) {
    int g = blockIdx.x * 256 + threadIdx.x;   // 65536 = 256 i * 256 o
    int i = g >> 8;
    int o = g & 255;
    const float4* src = (const float4*)(C + (size_t)i * (OUT_DIM * NDEG) + o * NDEG);
    float4 a = src[0];
    float4 b = src[1];
    bf16x8 v;
    v[0] = (__bf16)a.x; v[1] = (__bf16)a.y; v[2] = (__bf16)a.z; v[3] = (__bf16)a.w;
    v[4] = (__bf16)b.x; v[5] = (__bf16)b.y; v[6] = (__bf16)b.z; v[7] = (__bf16)b.w;
    *(bf16x8*)(Bt + (size_t)o * KTOT + i * NDEG) = v;
}

// ---------------------------------------------------------------------------
// Kernel 2: fused tanh + Hermite featurize + bf16 MFMA GEMM.
// Round 2: BM 128->64 (grid 1024 = 4 blocks/CU; grid of 512 was the hard
// occupancy cap last round) + register prefetch of next chunk's x and Bt
// issued before the MFMA phase so global latency hides behind MFMA.
// Tile 64x128, 4 waves of 32x64 (2x4 frags of 16x16x32).
// ---------------------------------------------------------------------------
__global__ __launch_bounds__(256, 4) void hermite_mfma(const float* __restrict__ x,
                                                       const __bf16* __restrict__ Bt,
                                                       float* __restrict__ out) {
    __shared__ __align__(16) __bf16 Alds[BM * LDT];   //  9216 B
    __shared__ __align__(16) __bf16 Blds[BN * LDT];   // 18432 B  (27.6 KB total)

    const int tid  = threadIdx.x;
    const int bm   = blockIdx.x;   // 0..511
    const int bn   = blockIdx.y;   // 0..1
    const int wave = tid >> 6;
    const int lane = tid & 63;
    const int wr   = (wave >> 1) * 32;   // wave row origin in tile
    const int wc   = (wave & 1) * 64;    // wave col origin in tile
    const int lrow = lane & 15;
    const int quad = lane >> 4;

    // A staging: thread -> (row am, 2 consecutive inputs starting at ah)
    const int am = tid >> 2;             // 0..63
    const int ah = (tid & 3) * 2;        // 0,2,4,6
    const float* xrow = x + (size_t)(bm * BM + am) * INPUT_DIM + ah;

    // B staging: thread -> (rows bo+32q, 8-elem segment bseg)
    const int bo   = tid >> 3;           // 0..31
    const int bseg = (tid & 7) * 8;      // 0..56
    const __bf16* bbase = Bt + (size_t)(bn * BN + bo) * KTOT + bseg;

    f32x4 acc[2][4] = {};

    // ---- prologue prefetch (chunk 0) ----
    float2 xv = *(const float2*)(xrow);
    uint4 bv[4];
    #pragma unroll
    for (int q = 0; q < 4; ++q)
        bv[q] = *(const uint4*)(bbase + (size_t)q * 32 * KTOT);

    for (int kc = 0; kc < NK; ++kc) {
        // ---- stage A: tanh + physicists' Hermite recurrence (fp32), pack bf16 ----
        #pragma unroll
        for (int j = 0; j < 2; ++j) {
            float xs = (&xv.x)[j];
            // tanh(x) = 1 - 2/(e^{2x}+1): robust for all x (overflow -> t=1)
            float e = __expf(2.0f * xs);
            float t = 1.0f - 2.0f / (e + 1.0f);
            bf16x8 v;
            float hm2 = 1.0f;            // H_0
            float hm1 = 2.0f * t;        // H_1
            v[0] = (__bf16)hm2;
            v[1] = (__bf16)hm1;
            #pragma unroll
            for (int d = 2; d < 8; ++d) {
                float h = 2.0f * t * hm1 - 2.0f * (float)(d - 1) * hm2;
                v[d] = (__bf16)h;
                hm2 = hm1; hm1 = h;
            }
            *(bf16x8*)(&Alds[am * LDT + (ah + j) * 8]) = v;
        }

        // ---- stage B^T chunk from prefetch regs ----
        #pragma unroll
        for (int q = 0; q < 4; ++q)
            *(uint4*)(&Blds[(bo + 32 * q) * LDT + bseg]) = bv[q];

        __syncthreads();

        // ---- issue next chunk's global loads (hidden behind MFMA below) ----
        const int kn = (kc + 1 < NK) ? kc + 1 : kc;
        xv = *(const float2*)(xrow + kn * 8);
        #pragma unroll
        for (int q = 0; q < 4; ++q)
            bv[q] = *(const uint4*)(bbase + (size_t)q * 32 * KTOT + kn * BK);

        // ---- MFMA: 2 k-steps of 32, 2x4 frags per wave ----
        #pragma unroll
        for (int ki = 0; ki < 2; ++ki) {
            bf16x8 af[2], bfr[4];
            #pragma unroll
            for (int mi = 0; mi < 2; ++mi)
                af[mi] = *(const bf16x8*)(&Alds[(wr + mi * 16 + lrow) * LDT + ki * 32 + quad * 8]);
            #pragma unroll
            for (int ni = 0; ni < 4; ++ni)
                bfr[ni] = *(const bf16x8*)(&Blds[(wc + ni * 16 + lrow) * LDT + ki * 32 + quad * 8]);
            #pragma unroll
            for (int mi = 0; mi < 2; ++mi)
                #pragma unroll
                for (int ni = 0; ni < 4; ++ni)
                    acc[mi][ni] = __builtin_amdgcn_mfma_f32_16x16x32_bf16(
                        af[mi], bfr[ni], acc[mi][ni], 0, 0, 0);
        }

        __syncthreads();
    }

    // ---- epilogue: C/D layout col=lane&15, row=quad*4+reg (m89-verified) ----
    #pragma unroll
    for (int mi = 0; mi < 2; ++mi) {
        #pragma unroll
        for (int r = 0; r < 4; ++r) {
            int row = bm * BM + wr + mi * 16 + quad * 4 + r;
            float* orow = out + (size_t)row * OUT_DIM + bn * BN + wc + lrow;
            #pragma unroll
            for (int ni = 0; ni < 4; ++ni)
                orow[ni * 16] = acc[mi][ni][r];
        }
    }
}

// ---------------------------------------------------------------------------
extern "C" void kernel_launch(void* const* d_in, const int* in_sizes, int n_in,
                              void* d_out, int out_size, void* d_ws, size_t ws_size,
                              hipStream_t stream) {
    const float* x = (const float*)d_in[0];          // [16,2048,256] fp32
    const float* C = (const float*)d_in[1];          // [256,256,8]  fp32
    float* out = (float*)d_out;                      // [16,2048,256] fp32
    __bf16* Bt = (__bf16*)d_ws;                      // [256][2048] bf16, 1 MB scratch

    reorder_coeffs<<<dim3((INPUT_DIM * OUT_DIM) / 256), dim3(256), 0, stream>>>(C, Bt);
    hermite_mfma<<<dim3(NROWS / BM, OUT_DIM / BN), dim3(256), 0, stream>>>(x, Bt, out);
}

// Round 3
// 134.051 us; speedup vs baseline: 1.7490x; 1.7490x over previous
//
#include <hip/hip_runtime.h>
#include <hip/hip_bf16.h>
#include <math.h>

#define INPUT_DIM 256
#define OUT_DIM   256
#define NDEG      8                    // degree+1
#define KTOT      (INPUT_DIM * NDEG)   // 2048
#define NROWS     (16 * 2048)          // 32768

#define BM  64
#define BN  128
#define BK  64                         // 8 inputs * 8 degrees per K-chunk
#define NK  (KTOT / BK)                // 32
#define LDT 72                         // padded LDS row stride (144 B -> 2-way-only conflicts, free per m136)

typedef __bf16 bf16x8 __attribute__((ext_vector_type(8)));
typedef float  f32x4  __attribute__((ext_vector_type(4)));

// ---------------------------------------------------------------------------
// Kernel 1: reorder coeffs  C[i][o][d] (fp32)  ->  Bt[o][i*8+d] (bf16)
// ---------------------------------------------------------------------------
__global__ __launch_bounds__(256) void reorder_coeffs(const float* __restrict__ C,
                                                      __bf16* __restrict__ Bt) {
    int g = blockIdx.x * 256 + threadIdx.x;   // 65536 = 256 i * 256 o
    int i = g >> 8;
    int o = g & 255;
    const float4* src = (const float4*)(C + (size_t)i * (OUT_DIM * NDEG) + o * NDEG);
    float4 a = src[0];
    float4 b = src[1];
    bf16x8 v;
    v[0] = (__bf16)a.x; v[1] = (__bf16)a.y; v[2] = (__bf16)a.z; v[3] = (__bf16)a.w;
    v[4] = (__bf16)b.x; v[5] = (__bf16)b.y; v[6] = (__bf16)b.z; v[7] = (__bf16)b.w;
    *(bf16x8*)(Bt + (size_t)o * KTOT + i * NDEG) = v;
}

// ---------------------------------------------------------------------------
// Kernel 2: fused tanh + Hermite featurize + bf16 MFMA GEMM.
// Round 3: keep BM=64 (grid 1024 = 4 blocks/CU; Round 1's grid of 512 was
// the hard occupancy cap) but REVERT the cross-barrier register prefetch —
// it spilled to scratch (WRITE_SIZE 32->244 MB in Round 2) and made the
// kernel scratch-traffic-bound. Staging is in-phase: B global loads issue
// first, tanh/Hermite VALU work overlaps their latency, nothing lives
// across __syncthreads. Inter-wave TLP (16 waves/CU) hides in-phase latency.
// Tile 64x128, 4 waves of 32x64 (2x4 frags of 16x16x32).
// ---------------------------------------------------------------------------
__global__ __launch_bounds__(256, 4) void hermite_mfma(const float* __restrict__ x,
                                                       const __bf16* __restrict__ Bt,
                                                       float* __restrict__ out) {
    __shared__ __align__(16) __bf16 Alds[BM * LDT];   //  9216 B
    __shared__ __align__(16) __bf16 Blds[BN * LDT];   // 18432 B  (27.6 KB total)

    const int tid  = threadIdx.x;
    const int bm   = blockIdx.x;   // 0..511
    const int bn   = blockIdx.y;   // 0..1
    const int wave = tid >> 6;
    const int lane = tid & 63;
    const int wr   = (wave >> 1) * 32;   // wave row origin in tile
    const int wc   = (wave & 1) * 64;    // wave col origin in tile
    const int lrow = lane & 15;
    const int quad = lane >> 4;

    // A staging: thread -> (row am, 2 consecutive inputs starting at ah)
    const int am = tid >> 2;             // 0..63
    const int ah = (tid & 3) * 2;        // 0,2,4,6
    const float* xrow = x + (size_t)(bm * BM + am) * INPUT_DIM + ah;

    // B staging: thread -> (rows bo+32q, 8-elem segment bseg)
    const int bo   = tid >> 3;           // 0..31
    const int bseg = (tid & 7) * 8;      // 0..56
    const __bf16* bbase = Bt + (size_t)(bn * BN + bo) * KTOT + bseg;

    f32x4 acc[2][4] = {};

    for (int kc = 0; kc < NK; ++kc) {
        // ---- issue B^T chunk loads first (latency overlaps featurize VALU) ----
        uint4 bv0 = *(const uint4*)(bbase + (size_t)0 * 32 * KTOT + kc * BK);
        uint4 bv1 = *(const uint4*)(bbase + (size_t)1 * 32 * KTOT + kc * BK);
        uint4 bv2 = *(const uint4*)(bbase + (size_t)2 * 32 * KTOT + kc * BK);
        uint4 bv3 = *(const uint4*)(bbase + (size_t)3 * 32 * KTOT + kc * BK);
        float2 xv = *(const float2*)(xrow + kc * 8);

        // ---- stage A: tanh + physicists' Hermite recurrence (fp32), pack bf16 ----
        #pragma unroll
        for (int j = 0; j < 2; ++j) {
            float xs = (&xv.x)[j];
            // tanh(x) = 1 - 2/(e^{2x}+1): robust for all x (overflow -> t=1)
            float e = __expf(2.0f * xs);
            float t = 1.0f - 2.0f / (e + 1.0f);
            bf16x8 v;
            float hm2 = 1.0f;            // H_0
            float hm1 = 2.0f * t;        // H_1
            v[0] = (__bf16)hm2;
            v[1] = (__bf16)hm1;
            #pragma unroll
            for (int d = 2; d < 8; ++d) {
                float h = 2.0f * t * hm1 - 2.0f * (float)(d - 1) * hm2;
                v[d] = (__bf16)h;
                hm2 = hm1; hm1 = h;
            }
            *(bf16x8*)(&Alds[am * LDT + (ah + j) * 8]) = v;
        }

        // ---- stage B^T chunk to LDS (waits on the loads issued above) ----
        *(uint4*)(&Blds[(bo +  0) * LDT + bseg]) = bv0;
        *(uint4*)(&Blds[(bo + 32) * LDT + bseg]) = bv1;
        *(uint4*)(&Blds[(bo + 64) * LDT + bseg]) = bv2;
        *(uint4*)(&Blds[(bo + 96) * LDT + bseg]) = bv3;

        __syncthreads();

        // ---- MFMA: 2 k-steps of 32, 2x4 frags per wave ----
        #pragma unroll
        for (int ki = 0; ki < 2; ++ki) {
            bf16x8 af[2], bfr[4];
            #pragma unroll
            for (int mi = 0; mi < 2; ++mi)
                af[mi] = *(const bf16x8*)(&Alds[(wr + mi * 16 + lrow) * LDT + ki * 32 + quad * 8]);
            #pragma unroll
            for (int ni = 0; ni < 4; ++ni)
                bfr[ni] = *(const bf16x8*)(&Blds[(wc + ni * 16 + lrow) * LDT + ki * 32 + quad * 8]);
            #pragma unroll
            for (int mi = 0; mi < 2; ++mi)
                #pragma unroll
                for (int ni = 0; ni < 4; ++ni)
                    acc[mi][ni] = __builtin_amdgcn_mfma_f32_16x16x32_bf16(
                        af[mi], bfr[ni], acc[mi][ni], 0, 0, 0);
        }

        __syncthreads();
    }

    // ---- epilogue: C/D layout col=lane&15, row=quad*4+reg (m89-verified) ----
    #pragma unroll
    for (int mi = 0; mi < 2; ++mi) {
        #pragma unroll
        for (int r = 0; r < 4; ++r) {
            int row = bm * BM + wr + mi * 16 + quad * 4 + r;
            float* orow = out + (size_t)row * OUT_DIM + bn * BN + wc + lrow;
            #pragma unroll
            for (int ni = 0; ni < 4; ++ni)
                orow[ni * 16] = acc[mi][ni][r];
        }
    }
}

// ---------------------------------------------------------------------------
extern "C" void kernel_launch(void* const* d_in, const int* in_sizes, int n_in,
                              void* d_out, int out_size, void* d_ws, size_t ws_size,
                              hipStream_t stream) {
    const float* x = (const float*)d_in[0];          // [16,2048,256] fp32
    const float* C = (const float*)d_in[1];          // [256,256,8]  fp32
    float* out = (float*)d_out;                      // [16,2048,256] fp32
    __bf16* Bt = (__bf16*)d_ws;                      // [256][2048] bf16, 1 MB scratch

    reorder_coeffs<<<dim3((INPUT_DIM * OUT_DIM) / 256), dim3(256), 0, stream>>>(C, Bt);
    hermite_mfma<<<dim3(NROWS / BM, OUT_DIM / BN), dim3(256), 0, stream>>>(x, Bt, out);
}

// Round 4
// 123.861 us; speedup vs baseline: 1.8929x; 1.0823x over previous
//
#include <hip/hip_runtime.h>
#include <hip/hip_bf16.h>
#include <math.h>

#define INPUT_DIM 256
#define OUT_DIM   256
#define NDEG      8                    // degree+1
#define KTOT      (INPUT_DIM * NDEG)   // 2048
#define NROWS     (16 * 2048)          // 32768

#define BM  64
#define BN  128
#define BK  64                         // 8 inputs * 8 degrees per K-chunk
#define NK  (KTOT / BK)                // 32
#define LDT 72                         // padded A-LDS row stride (2-way-only conflicts, free per m136)
#define CHUNK_ELEMS 8192               // one (bn,kc) B-chunk: 128 o * 64 k bf16 = 16 KB

typedef __bf16 bf16x8 __attribute__((ext_vector_type(8)));
typedef float  f32x4  __attribute__((ext_vector_type(4)));

// ---------------------------------------------------------------------------
// Kernel 1: reorder + swizzle coeffs C[i][o][d] (fp32) -> Bt_sw (bf16).
// Bt_sw is laid out as the exact linear LDS image consumed by global_load_lds:
//   chunk(bn,kc) base = (bn*32+kc)*8192 elems; within chunk:
//   elem offset = p*1024 + o_local*8 + r   (p = i&7 input-in-chunk, r = d)
// MFMA-phase ds_read_b128 of this layout has bank pattern (o*4)%32 -> 2-way
// aliasing only (free, m136).
// ---------------------------------------------------------------------------
__global__ __launch_bounds__(256) void reorder_coeffs(const float* __restrict__ C,
                                                      __bf16* __restrict__ Bt) {
    int g = blockIdx.x * 256 + threadIdx.x;   // 65536 = 256 i * 256 o
    int i = g >> 8;
    int o = g & 255;
    const float4* src = (const float4*)(C + (size_t)i * (OUT_DIM * NDEG) + o * NDEG);
    float4 a = src[0];
    float4 b = src[1];
    bf16x8 v;
    v[0] = (__bf16)a.x; v[1] = (__bf16)a.y; v[2] = (__bf16)a.z; v[3] = (__bf16)a.w;
    v[4] = (__bf16)b.x; v[5] = (__bf16)b.y; v[6] = (__bf16)b.z; v[7] = (__bf16)b.w;
    int bn = o >> 7;          // which BN tile
    int ol = o & 127;         // o within tile
    int kc = i >> 3;          // K-chunk
    int p  = i & 7;           // input-in-chunk (panel)
    size_t dst = (size_t)(bn * 32 + kc) * CHUNK_ELEMS + p * 1024 + ol * 8;
    *(bf16x8*)(Bt + dst) = v;   // 16B-aligned
}

// ---------------------------------------------------------------------------
// Kernel 2: fused tanh + Hermite featurize + bf16 MFMA GEMM.
// Round 4: B staging via __builtin_amdgcn_global_load_lds width=16 (the
// m93->m97 1.7x lever) from the pre-swizzled Bt_sw — no VGPR round-trip,
// no ds_write for B. x load issued before the 4 glds so the featurize
// waits at vmcnt(4) instead of draining the DMA queue.
// Tile 64x128, 4 waves of 32x64 (2x4 frags of 16x16x32), grid 1024 = 4/CU.
// ---------------------------------------------------------------------------
__global__ __launch_bounds__(256, 4) void hermite_mfma(const float* __restrict__ x,
                                                       const __bf16* __restrict__ Bt,
                                                       float* __restrict__ out) {
    __shared__ __align__(16) __bf16 Alds[BM * LDT];       //  9216 B (padded)
    __shared__ __align__(16) __bf16 Blds[CHUNK_ELEMS];    // 16384 B (linear DMA image)

    const int tid  = threadIdx.x;
    const int bm   = blockIdx.x;   // 0..511
    const int bn   = blockIdx.y;   // 0..1
    const int wave = tid >> 6;
    const int lane = tid & 63;
    const int wr   = (wave >> 1) * 32;   // wave row origin in tile
    const int wc   = (wave & 1) * 64;    // wave col origin in tile
    const int lrow = lane & 15;
    const int quad = lane >> 4;

    // A staging: thread -> (row am, 2 consecutive inputs starting at ah)
    const int am = tid >> 2;             // 0..63
    const int ah = (tid & 3) * 2;        // 0,2,4,6
    const float* xrow = x + (size_t)(bm * BM + am) * INPUT_DIM + ah;

    // B staging: wave w DMAs bytes [w*4K, w*4K+4K) of the 16 KB chunk, 4 x 1 KB
    const __bf16* chunk0 = Bt + (size_t)bn * 32 * CHUNK_ELEMS;  // + kc*CHUNK_ELEMS per iter
    const int woff = wave * 2048 + lane * 8;    // elems within chunk (per-lane 16 B)

    f32x4 acc[2][4] = {};

    for (int kc = 0; kc < NK; ++kc) {
        // ---- x load first (featurize waits vmcnt(4), not a full drain) ----
        float2 xv = *(const float2*)(xrow + kc * 8);

        // ---- B chunk: 4 global_load_lds dwordx4 per wave (1 KB each) ----
        const __bf16* gsrc = chunk0 + (size_t)kc * CHUNK_ELEMS + woff;
        #pragma unroll
        for (int i = 0; i < 4; ++i) {
            __builtin_amdgcn_global_load_lds(
                (const __attribute__((address_space(1))) void*)(gsrc + i * 512),
                (__attribute__((address_space(3))) void*)(&Blds[wave * 2048 + i * 512 + lane * 8]),
                16, 0, 0);
        }

        // ---- stage A: tanh + physicists' Hermite recurrence (fp32), pack bf16 ----
        #pragma unroll
        for (int j = 0; j < 2; ++j) {
            float xs = (&xv.x)[j];
            // tanh(x) = 1 - 2/(e^{2x}+1): robust for all x (overflow -> t=1)
            float e = __expf(2.0f * xs);
            float t = 1.0f - 2.0f / (e + 1.0f);
            bf16x8 v;
            float hm2 = 1.0f;            // H_0
            float hm1 = 2.0f * t;        // H_1
            v[0] = (__bf16)hm2;
            v[1] = (__bf16)hm1;
            #pragma unroll
            for (int d = 2; d < 8; ++d) {
                float h = 2.0f * t * hm1 - 2.0f * (float)(d - 1) * hm2;
                v[d] = (__bf16)h;
                hm2 = hm1; hm1 = h;
            }
            *(bf16x8*)(&Alds[am * LDT + (ah + j) * 8]) = v;
        }

        __syncthreads();   // drains glds (vmcnt) + A ds_writes (lgkm)

        // ---- MFMA: 2 k-steps of 32, 2x4 frags per wave ----
        #pragma unroll
        for (int ki = 0; ki < 2; ++ki) {
            bf16x8 af[2], bfr[4];
            #pragma unroll
            for (int mi = 0; mi < 2; ++mi)
                af[mi] = *(const bf16x8*)(&Alds[(wr + mi * 16 + lrow) * LDT + ki * 32 + quad * 8]);
            #pragma unroll
            for (int ni = 0; ni < 4; ++ni)
                bfr[ni] = *(const bf16x8*)(&Blds[((ki * 4 + quad) * 128 + (wc + ni * 16 + lrow)) * 8]);
            #pragma unroll
            for (int mi = 0; mi < 2; ++mi)
                #pragma unroll
                for (int ni = 0; ni < 4; ++ni)
                    acc[mi][ni] = __builtin_amdgcn_mfma_f32_16x16x32_bf16(
                        af[mi], bfr[ni], acc[mi][ni], 0, 0, 0);
        }

        __syncthreads();
    }

    // ---- epilogue: C/D layout col=lane&15, row=quad*4+reg (m89-verified) ----
    #pragma unroll
    for (int mi = 0; mi < 2; ++mi) {
        #pragma unroll
        for (int r = 0; r < 4; ++r) {
            int row = bm * BM + wr + mi * 16 + quad * 4 + r;
            float* orow = out + (size_t)row * OUT_DIM + bn * BN + wc + lrow;
            #pragma unroll
            for (int ni = 0; ni < 4; ++ni)
                orow[ni * 16] = acc[mi][ni][r];
        }
    }
}

// ---------------------------------------------------------------------------
extern "C" void kernel_launch(void* const* d_in, const int* in_sizes, int n_in,
                              void* d_out, int out_size, void* d_ws, size_t ws_size,
                              hipStream_t stream) {
    const float* x = (const float*)d_in[0];          // [16,2048,256] fp32
    const float* C = (const float*)d_in[1];          // [256,256,8]  fp32
    float* out = (float*)d_out;                      // [16,2048,256] fp32
    __bf16* Bt = (__bf16*)d_ws;                      // swizzled [2][32][8192] bf16, 1 MB scratch

    reorder_coeffs<<<dim3((INPUT_DIM * OUT_DIM) / 256), dim3(256), 0, stream>>>(C, Bt);
    hermite_mfma<<<dim3(NROWS / BM, OUT_DIM / BN), dim3(256), 0, stream>>>(x, Bt, out);
}

// Round 5
// 121.634 us; speedup vs baseline: 1.9275x; 1.0183x over previous
//
#include <hip/hip_runtime.h>
#include <hip/hip_bf16.h>
#include <math.h>

#define INPUT_DIM 256
#define OUT_DIM   256
#define NDEG      8                    // degree+1
#define KTOT      (INPUT_DIM * NDEG)   // 2048
#define NROWS     (16 * 2048)          // 32768

#define BM  64
#define BN  256                        // whole output dim: featurize computed ONCE per x elem
#define BK  64                         // 8 inputs * 8 degrees per K-chunk
#define NK  (KTOT / BK)                // 32
#define LDT 72                         // padded A-LDS row stride (2-way-only conflicts, free per m136)
#define CHUNK_ELEMS 16384              // one kc B-chunk: 256 o * 64 k bf16 = 32 KB

typedef __bf16 bf16x8 __attribute__((ext_vector_type(8)));
typedef float  f32x4  __attribute__((ext_vector_type(4)));

// ---------------------------------------------------------------------------
// Kernel 1: reorder + swizzle coeffs C[i][o][d] (fp32) -> Bt_sw (bf16).
// Bt_sw is the exact linear LDS image consumed by global_load_lds:
//   chunk(kc) base = kc*16384 elems; within chunk:
//   elem offset = p*2048 + o*8 + r   (p = i&7 input-in-chunk, r = d)
// MFMA-phase ds_read_b128 bank pattern (o*4)%32 -> 2-way aliasing only (free).
// ---------------------------------------------------------------------------
__global__ __launch_bounds__(256) void reorder_coeffs(const float* __restrict__ C,
                                                      __bf16* __restrict__ Bt) {
    int g = blockIdx.x * 256 + threadIdx.x;   // 65536 = 256 i * 256 o
    int i = g >> 8;
    int o = g & 255;
    const float4* src = (const float4*)(C + (size_t)i * (OUT_DIM * NDEG) + o * NDEG);
    float4 a = src[0];
    float4 b = src[1];
    bf16x8 v;
    v[0] = (__bf16)a.x; v[1] = (__bf16)a.y; v[2] = (__bf16)a.z; v[3] = (__bf16)a.w;
    v[4] = (__bf16)b.x; v[5] = (__bf16)b.y; v[6] = (__bf16)b.z; v[7] = (__bf16)b.w;
    int kc = i >> 3;          // K-chunk
    int p  = i & 7;           // input-in-chunk (panel)
    size_t dst = (size_t)kc * CHUNK_ELEMS + p * 2048 + o * 8;
    *(bf16x8*)(Bt + dst) = v;   // 16B-aligned
}

// ---------------------------------------------------------------------------
// Kernel 2: fused tanh + Hermite featurize + bf16 MFMA GEMM.
// Round 5: BN=256 (nbn 2->1) kills the 2x featurize/x-load duplication that
// dominated VALUBusy. 512-thread blocks (8 waves of 32x64), grid 512 =
// 2 blocks/CU = 16 waves/CU (same residency as R4, half the featurize).
// B staging stays global_load_lds width=16 from pre-swizzled Bt (R4 lever);
// A featurize 1 eval/thread/iter into padded LDS.
// ---------------------------------------------------------------------------
__global__ __launch_bounds__(512, 4) void hermite_mfma(const float* __restrict__ x,
                                                       const __bf16* __restrict__ Bt,
                                                       float* __restrict__ out) {
    __shared__ __align__(16) __bf16 Alds[BM * LDT];       //  9216 B (padded)
    __shared__ __align__(16) __bf16 Blds[CHUNK_ELEMS];    // 32768 B (linear DMA image)

    const int tid  = threadIdx.x;
    const int bm   = blockIdx.x;         // 0..511
    const int wave = tid >> 6;           // 0..7
    const int lane = tid & 63;
    const int wr   = (wave >> 2) * 32;   // wave row origin in tile (0,32)
    const int wc   = (wave & 3) * 64;    // wave col origin in tile (0,64,128,192)
    const int lrow = lane & 15;
    const int quad = lane >> 4;

    // A staging: thread -> (row am, single input ah) : 512 threads = 64x8 evals
    const int am = tid >> 3;             // 0..63
    const int ah = tid & 7;              // 0..7
    const float* xptr = x + (size_t)(bm * BM + am) * INPUT_DIM + ah;

    // B staging: wave w DMAs bytes [w*4K, w*4K+4K) of the 32 KB chunk, 4 x 1 KB
    const int wbase = wave * 2048 + lane * 8;   // elems within chunk (per-lane 16 B)

    f32x4 acc[2][4] = {};

    for (int kc = 0; kc < NK; ++kc) {
        // ---- x load first (featurize waits vmcnt(4), not a full drain) ----
        float xs = xptr[kc * 8];

        // ---- B chunk: 4 global_load_lds dwordx4 per wave (1 KB each) ----
        const __bf16* gsrc = Bt + (size_t)kc * CHUNK_ELEMS + wbase;
        #pragma unroll
        for (int i = 0; i < 4; ++i) {
            __builtin_amdgcn_global_load_lds(
                (const __attribute__((address_space(1))) void*)(gsrc + i * 512),
                (__attribute__((address_space(3))) void*)(&Blds[wbase + i * 512]),
                16, 0, 0);
        }

        // ---- stage A: tanh + physicists' Hermite recurrence (fp32), pack bf16 ----
        {
            // tanh(x) = 1 - 2/(e^{2x}+1): robust for all x (overflow -> t=1)
            float e = __expf(2.0f * xs);
            float t = 1.0f - 2.0f / (e + 1.0f);
            bf16x8 v;
            float hm2 = 1.0f;            // H_0
            float hm1 = 2.0f * t;        // H_1
            v[0] = (__bf16)hm2;
            v[1] = (__bf16)hm1;
            #pragma unroll
            for (int d = 2; d < 8; ++d) {
                float h = 2.0f * t * hm1 - 2.0f * (float)(d - 1) * hm2;
                v[d] = (__bf16)h;
                hm2 = hm1; hm1 = h;
            }
            *(bf16x8*)(&Alds[am * LDT + ah * 8]) = v;
        }

        __syncthreads();   // drains glds (vmcnt) + A ds_writes (lgkm)

        // ---- MFMA: 2 k-steps of 32, 2x4 frags per wave ----
        #pragma unroll
        for (int ki = 0; ki < 2; ++ki) {
            bf16x8 af[2], bfr[4];
            #pragma unroll
            for (int mi = 0; mi < 2; ++mi)
                af[mi] = *(const bf16x8*)(&Alds[(wr + mi * 16 + lrow) * LDT + ki * 32 + quad * 8]);
            #pragma unroll
            for (int ni = 0; ni < 4; ++ni)
                bfr[ni] = *(const bf16x8*)(&Blds[(ki * 4 + quad) * 2048 + (wc + ni * 16 + lrow) * 8]);
            #pragma unroll
            for (int mi = 0; mi < 2; ++mi)
                #pragma unroll
                for (int ni = 0; ni < 4; ++ni)
                    acc[mi][ni] = __builtin_amdgcn_mfma_f32_16x16x32_bf16(
                        af[mi], bfr[ni], acc[mi][ni], 0, 0, 0);
        }

        __syncthreads();
    }

    // ---- epilogue: C/D layout col=lane&15, row=quad*4+reg (m89-verified) ----
    #pragma unroll
    for (int mi = 0; mi < 2; ++mi) {
        #pragma unroll
        for (int r = 0; r < 4; ++r) {
            int row = bm * BM + wr + mi * 16 + quad * 4 + r;
            float* orow = out + (size_t)row * OUT_DIM + wc + lrow;
            #pragma unroll
            for (int ni = 0; ni < 4; ++ni)
                orow[ni * 16] = acc[mi][ni][r];
        }
    }
}

// ---------------------------------------------------------------------------
extern "C" void kernel_launch(void* const* d_in, const int* in_sizes, int n_in,
                              void* d_out, int out_size, void* d_ws, size_t ws_size,
                              hipStream_t stream) {
    const float* x = (const float*)d_in[0];          // [16,2048,256] fp32
    const float* C = (const float*)d_in[1];          // [256,256,8]  fp32
    float* out = (float*)d_out;                      // [16,2048,256] fp32
    __bf16* Bt = (__bf16*)d_ws;                      // swizzled [32][16384] bf16, 1 MB scratch

    reorder_coeffs<<<dim3((INPUT_DIM * OUT_DIM) / 256), dim3(256), 0, stream>>>(C, Bt);
    hermite_mfma<<<dim3(NROWS / BM), dim3(512), 0, stream>>>(x, Bt, out);
}